// Round 5
// baseline (542.157 us; speedup 1.0000x reference)
//
#include <hip/hip_runtime.h>

// HierarchicalTimeAttention  B=4, T=4096, H=1024, D=4
// ROOT CAUSE (r4 bisect): d_out is FLOAT32 (reference outputs f32; out_npz
// 62MB = f32). Previous rounds packed bf16 u16 pairs into f32 slots and put
// new_state at a u16 offset = middle of output 0. MFMA layout verified OK
// (bf16-MFMA pipeline == f32-VALU pipeline to absmax digit).
// This round: MFMA pipeline + f32 output writes.
#define B_ 4
#define T_ 4096
#define H_ 1024
#define D_ 4
#define M_ (B_ * T_)          // 16384
#define OUT_MAIN (M_ * H_)    // 16,777,216 (f32 elements)

// ws (bytes), total ~40.3MB:
#define WS_BUF  0UL           // bf16 [M][H]: k -> kv -> o   (32MB)
#define WS_WK   33554432UL    // bf16 Wk [H][H] (2MB)
#define WS_WV   35651584UL
#define WS_WR   37748736UL
#define WS_WO   39845888UL
#define WS_LGW  41943040UL    // f32 softmax weights [M][4] (256KB)
#define WS_DEC  42205184UL    // f32 decayed_state0 [B][D][H] (64KB)

typedef __bf16 bf16x8 __attribute__((ext_vector_type(8)));
typedef unsigned short u16x4 __attribute__((ext_vector_type(4)));
typedef float f32x4 __attribute__((ext_vector_type(4)));

__device__ __forceinline__ float b2f(unsigned short u) {
    union { unsigned int i; float f; } c;
    c.i = ((unsigned int)u) << 16;
    return c.f;
}
__device__ __forceinline__ unsigned short f2b(float f) {
    union { float f; unsigned int i; } c;
    c.f = f;
    unsigned int x = c.i;
    unsigned int r = (x + 0x7FFFu + ((x >> 16) & 1u)) >> 16;  // RNE
    return (unsigned short)r;
}

// ---------------------------------------------------------------------------
// f32 -> bf16, 4 elems/thread, grid-stride
// ---------------------------------------------------------------------------
__global__ __launch_bounds__(256) void cvt_k(const float* __restrict__ s,
                                             unsigned short* __restrict__ d, int n4)
{
    int i = blockIdx.x * 256 + threadIdx.x;
    const int str = gridDim.x * 256;
    for (; i < n4; i += str) {
        const f32x4 v = ((const f32x4*)s)[i];
        u16x4 o;
        o[0] = f2b(v[0]); o[1] = f2b(v[1]); o[2] = f2b(v[2]); o[3] = f2b(v[3]);
        ((u16x4*)d)[i] = o;
    }
}

// ---------------------------------------------------------------------------
// GEMM: C[M][N] = A[M][K] @ W[N][K]^T  (bf16 in, f32 accum)
// 128x128 block tile, 4 waves of 64x64, mfma_f32_16x16x32_bf16.
//   A/B frag: row(col)=lane&15, k=8*(lane>>4)+i ; C/D: col=lane&15,
//   row=4*(lane>>4)+reg  [verified by r2==r4 pipeline agreement]
// EPI 0: C[idx] = bf16(acc)                                  (k)
// EPI 1: C[idx] = bf16(acc * b2f(C[idx]))                    (kv, in-place)
// EPI 2: C[idx] = bf16(sigmoid(acc)*(lw.dec + wsum*b2f(C)))  (o, in-place)
// EPI 3: outf[idx] = acc (f32)                               (final output)
// ---------------------------------------------------------------------------
template <int EPI>
__global__ __launch_bounds__(256) void gemm_bt(
    const unsigned short* __restrict__ A,
    const unsigned short* __restrict__ Wt,
    unsigned short* C,
    float* __restrict__ outf,
    const float* __restrict__ lgw,
    const float* __restrict__ dec,
    int M, int N, int K)
{
    const int tid  = threadIdx.x;
    const int wid  = tid >> 6;
    const int lane = tid & 63;
    const int lr   = lane & 15;
    const int lk   = (lane >> 4) << 3;
    const int row0 = blockIdx.x * 128 + (wid >> 1) * 64;
    const int col0 = blockIdx.y * 128 + (wid & 1) * 64;

    const unsigned short* Ap = A  + (size_t)(row0 + lr) * K + lk;
    const unsigned short* Wp = Wt + (size_t)(col0 + lr) * K + lk;

    f32x4 acc[4][4];
#pragma unroll
    for (int i = 0; i < 4; ++i)
#pragma unroll
        for (int j = 0; j < 4; ++j)
            acc[i][j] = (f32x4){0.f, 0.f, 0.f, 0.f};

    for (int k0 = 0; k0 < K; k0 += 32) {
        bf16x8 a[4], b[4];
#pragma unroll
        for (int i = 0; i < 4; ++i)
            a[i] = *(const bf16x8*)(Ap + (size_t)(i * 16) * K + k0);
#pragma unroll
        for (int i = 0; i < 4; ++i)
            b[i] = *(const bf16x8*)(Wp + (size_t)(i * 16) * K + k0);
#pragma unroll
        for (int mi = 0; mi < 4; ++mi)
#pragma unroll
            for (int ni = 0; ni < 4; ++ni)
                acc[mi][ni] = __builtin_amdgcn_mfma_f32_16x16x32_bf16(
                    a[mi], b[ni], acc[mi][ni], 0, 0, 0);
    }

    const int rbase = (lane >> 4) * 4;
    if (EPI == 0) {
#pragma unroll
        for (int mi = 0; mi < 4; ++mi)
#pragma unroll
            for (int j = 0; j < 4; ++j) {
                const size_t r = (size_t)(row0 + mi * 16 + rbase + j);
#pragma unroll
                for (int ni = 0; ni < 4; ++ni)
                    C[r * N + (col0 + ni * 16 + lr)] = f2b(acc[mi][ni][j]);
            }
    } else if (EPI == 1) {
#pragma unroll
        for (int mi = 0; mi < 4; ++mi)
#pragma unroll
            for (int j = 0; j < 4; ++j) {
                const size_t r = (size_t)(row0 + mi * 16 + rbase + j);
#pragma unroll
                for (int ni = 0; ni < 4; ++ni) {
                    const size_t idx = r * N + (col0 + ni * 16 + lr);
                    C[idx] = f2b(acc[mi][ni][j] * b2f(C[idx]));
                }
            }
    } else if (EPI == 2) {
        const int b = row0 >> 12;   // row/T_ (128-row blocks never straddle batch)
        float dcol[4][4];
#pragma unroll
        for (int ni = 0; ni < 4; ++ni)
#pragma unroll
            for (int d = 0; d < 4; ++d)
                dcol[ni][d] = dec[b * (D_ * H_) + d * H_ + (col0 + ni * 16 + lr)];
#pragma unroll
        for (int mi = 0; mi < 4; ++mi)
#pragma unroll
            for (int j = 0; j < 4; ++j) {
                const int r = row0 + mi * 16 + rbase + j;
                const f32x4 lw = *(const f32x4*)(lgw + (size_t)r * 4);
                const float wsum = lw[0] + lw[1] + lw[2] + lw[3];
#pragma unroll
                for (int ni = 0; ni < 4; ++ni) {
                    const size_t idx = (size_t)r * N + (col0 + ni * 16 + lr);
                    const float rv = 1.0f / (1.0f + __expf(-acc[mi][ni][j]));
                    const float w  = lw[0] * dcol[ni][0] + lw[1] * dcol[ni][1]
                                   + lw[2] * dcol[ni][2] + lw[3] * dcol[ni][3]
                                   + wsum * b2f(C[idx]);
                    C[idx] = f2b(rv * w);
                }
            }
    } else {
#pragma unroll
        for (int mi = 0; mi < 4; ++mi)
#pragma unroll
            for (int j = 0; j < 4; ++j) {
                const size_t r = (size_t)(row0 + mi * 16 + rbase + j);
#pragma unroll
                for (int ni = 0; ni < 4; ++ni)
                    outf[r * N + (col0 + ni * 16 + lr)] = acc[mi][ni][j];
            }
    }
}

// ---------------------------------------------------------------------------
// lgw[row][0..3] = softmax(x @ Wl^T + bl), one wave per row, f32.
// ---------------------------------------------------------------------------
__global__ __launch_bounds__(256) void logits_k(
    const float* __restrict__ X, const float* __restrict__ Wl,
    const float* __restrict__ bl, float* __restrict__ lgw)
{
    const int wid  = threadIdx.x >> 6;
    const int lane = threadIdx.x & 63;
    const int row  = blockIdx.x * 4 + wid;
    const float* xp = X + (size_t)row * H_;

    float acc[D_] = {0.f, 0.f, 0.f, 0.f};
    for (int h = lane * 4; h < H_; h += 256) {
        const f32x4 xv = *(const f32x4*)(xp + h);
#pragma unroll
        for (int d = 0; d < D_; ++d) {
            const f32x4 wv = *(const f32x4*)(Wl + d * H_ + h);
            acc[d] += xv[0] * wv[0] + xv[1] * wv[1] + xv[2] * wv[2] + xv[3] * wv[3];
        }
    }
#pragma unroll
    for (int off = 32; off; off >>= 1)
#pragma unroll
        for (int d = 0; d < D_; ++d) acc[d] += __shfl_xor(acc[d], off, 64);

    if (lane == 0) {
        float l[D_];
#pragma unroll
        for (int d = 0; d < D_; ++d) l[d] = acc[d] + bl[d];
        const float mx = fmaxf(fmaxf(l[0], l[1]), fmaxf(l[2], l[3]));
        float e[D_], s = 0.f;
#pragma unroll
        for (int d = 0; d < D_; ++d) { e[d] = __expf(l[d] - mx); s += e[d]; }
        const float inv = 1.0f / s;
        f32x4 o;
#pragma unroll
        for (int d = 0; d < D_; ++d) o[d] = e[d] * inv;
        *(f32x4*)(lgw + (size_t)row * 4) = o;
    }
}

// ---------------------------------------------------------------------------
__global__ void decstate_k(const float* __restrict__ state,
                           const float* __restrict__ tdm,
                           float* __restrict__ dec)
{
    const int i = blockIdx.x * blockDim.x + threadIdx.x;
    if (i >= B_ * D_ * H_) return;
    const int dh = i & (D_ * H_ - 1);
    dec[i] = state[i] * __expf(-__expf(tdm[dh]));
}

// ---------------------------------------------------------------------------
// new_state[b,d,h] = dec[b,d,h] + k_last*v_last, all-f32 exact path:
// one wave per (b,h): k_last = x[b,T-1,:].Wk[h,:], v_last = x[b,T-1,:].Wv[h,:]
// ---------------------------------------------------------------------------
__global__ __launch_bounds__(256) void newstate_k(
    const float* __restrict__ X, const float* __restrict__ Wk,
    const float* __restrict__ Wv, const float* __restrict__ dec,
    float* __restrict__ out2)
{
    const int wid  = threadIdx.x >> 6;
    const int lane = threadIdx.x & 63;
    const int row  = blockIdx.x * 4 + wid;   // 0..B*H-1
    const int b    = row >> 10;
    const int h    = row & (H_ - 1);
    const float* xp = X + ((size_t)(b * T_ + (T_ - 1))) * H_;

    float ak = 0.f, av = 0.f;
    for (int j = lane * 4; j < H_; j += 256) {
        const f32x4 xv = *(const f32x4*)(xp + j);
        const f32x4 wk = *(const f32x4*)(Wk + (size_t)h * H_ + j);
        const f32x4 wv = *(const f32x4*)(Wv + (size_t)h * H_ + j);
        ak += xv[0]*wk[0] + xv[1]*wk[1] + xv[2]*wk[2] + xv[3]*wk[3];
        av += xv[0]*wv[0] + xv[1]*wv[1] + xv[2]*wv[2] + xv[3]*wv[3];
    }
#pragma unroll
    for (int off = 32; off; off >>= 1) {
        ak += __shfl_xor(ak, off, 64);
        av += __shfl_xor(av, off, 64);
    }
    if (lane == 0) {
        const float kv = ak * av;
#pragma unroll
        for (int d = 0; d < D_; ++d)
            out2[(size_t)(b * D_ + d) * H_ + h] = dec[(b * D_ + d) * H_ + h] + kv;
    }
}

// ---------------------------------------------------------------------------
extern "C" void kernel_launch(void* const* d_in, const int* in_sizes, int n_in,
                              void* d_out, int out_size, void* d_ws, size_t ws_size,
                              hipStream_t stream)
{
    const float* x   = (const float*)d_in[0];
    const float* st  = (const float*)d_in[1];
    const float* tdm = (const float*)d_in[2];
    const float* Wl  = (const float*)d_in[3];
    const float* bl  = (const float*)d_in[4];
    const float* Wv  = (const float*)d_in[5];
    const float* Wk  = (const float*)d_in[6];
    const float* Wr  = (const float*)d_in[7];
    const float* Wo  = (const float*)d_in[8];
    float* out = (float*)d_out;                    // f32 output!

    char* ws = (char*)d_ws;
    unsigned short* buf  = (unsigned short*)(ws + WS_BUF);   // k -> kv -> o
    unsigned short* wk_b = (unsigned short*)(ws + WS_WK);
    unsigned short* wv_b = (unsigned short*)(ws + WS_WV);
    unsigned short* wr_b = (unsigned short*)(ws + WS_WR);
    unsigned short* wo_b = (unsigned short*)(ws + WS_WO);
    float* lgw = (float*)(ws + WS_LGW);
    float* dec = (float*)(ws + WS_DEC);

    // bf16 x scratch inside d_out's f32 output-0 region (33.5MB of 67.1MB);
    // final GEMM fully overwrites it afterwards.
    unsigned short* xb = (unsigned short*)out;

    cvt_k<<<2048, 256, 0, stream>>>(x,  xb,   OUT_MAIN / 4);
    cvt_k<<<512,  256, 0, stream>>>(Wk, wk_b, (H_ * H_) / 4);
    cvt_k<<<512,  256, 0, stream>>>(Wv, wv_b, (H_ * H_) / 4);
    cvt_k<<<512,  256, 0, stream>>>(Wr, wr_b, (H_ * H_) / 4);
    cvt_k<<<512,  256, 0, stream>>>(Wo, wo_b, (H_ * H_) / 4);

    const dim3 g(M_ / 128, H_ / 128), blk(256);

    // buf = k
    hipLaunchKernelGGL((gemm_bt<0>), g, blk, 0, stream, xb, wk_b, buf,
                       (float*)nullptr, (const float*)nullptr, (const float*)nullptr,
                       M_, H_, H_);
    // buf = kv
    hipLaunchKernelGGL((gemm_bt<1>), g, blk, 0, stream, xb, wv_b, buf,
                       (float*)nullptr, (const float*)nullptr, (const float*)nullptr,
                       M_, H_, H_);
    logits_k<<<M_ / 4, 256, 0, stream>>>(x, Wl, bl, lgw);
    decstate_k<<<(B_ * D_ * H_ + 255) / 256, 256, 0, stream>>>(st, tdm, dec);
    // new_state (f32 exact, independent of bf16 buffers)
    newstate_k<<<(B_ * H_) / 4, 256, 0, stream>>>(x, Wk, Wv, dec, out + OUT_MAIN);
    // buf = o = sigmoid(x@Wr^T) * (lw.dec + wsum*kv)
    hipLaunchKernelGGL((gemm_bt<2>), g, blk, 0, stream, xb, wr_b, buf,
                       (float*)nullptr, (const float*)lgw, (const float*)dec,
                       M_, H_, H_);
    // out = f32(o @ Wo^T)
    hipLaunchKernelGGL((gemm_bt<3>), g, blk, 0, stream, buf, wo_b, (unsigned short*)nullptr,
                       out, (const float*)nullptr, (const float*)nullptr,
                       M_, H_, H_);
}

// Round 6
// 287.532 us; speedup vs baseline: 1.8856x; 1.8856x over previous
//
#include <hip/hip_runtime.h>

// HierarchicalTimeAttention  B=4, T=4096, H=1024, D=4
// R6: GEMMs ported to the m97 structure (128x128 tile, 4 waves, BK=32,
// global_load_lds 16B staging, ds_read_b128 fragment loads, 2-barrier loop).
// R5 baseline: GEMM 155us each, MfmaUtil 8.9% (latency-bound, no LDS).
#define B_ 4
#define T_ 4096
#define H_ 1024
#define D_ 4
#define M_ (B_ * T_)          // 16384
#define OUT_MAIN (M_ * H_)    // 16,777,216 (f32 elements)

// ws (bytes), total ~40.3MB:
#define WS_BUF  0UL           // bf16 [M][H]: k -> kv -> o   (32MB)
#define WS_WK   33554432UL    // bf16 Wk [H][H] (2MB)
#define WS_WV   35651584UL
#define WS_WR   37748736UL
#define WS_WO   39845888UL
#define WS_LGW  41943040UL    // f32 softmax weights [M][4] (256KB)
#define WS_DEC  42205184UL    // f32 decayed_state0 [B][D][H] (64KB)

typedef __bf16 bf16x8 __attribute__((ext_vector_type(8)));
typedef unsigned short u16x4 __attribute__((ext_vector_type(4)));
typedef float f32x4 __attribute__((ext_vector_type(4)));

__device__ __forceinline__ float b2f(unsigned short u) {
    union { unsigned int i; float f; } c;
    c.i = ((unsigned int)u) << 16;
    return c.f;
}
__device__ __forceinline__ unsigned short f2b(float f) {
    union { float f; unsigned int i; } c;
    c.f = f;
    unsigned int x = c.i;
    unsigned int r = (x + 0x7FFFu + ((x >> 16) & 1u)) >> 16;  // RNE
    return (unsigned short)r;
}

// ---------------------------------------------------------------------------
// f32 -> bf16, 4 elems/thread, grid-stride
// ---------------------------------------------------------------------------
__global__ __launch_bounds__(256) void cvt_k(const float* __restrict__ s,
                                             unsigned short* __restrict__ d, int n4)
{
    int i = blockIdx.x * 256 + threadIdx.x;
    const int str = gridDim.x * 256;
    for (; i < n4; i += str) {
        const f32x4 v = ((const f32x4*)s)[i];
        u16x4 o;
        o[0] = f2b(v[0]); o[1] = f2b(v[1]); o[2] = f2b(v[2]); o[3] = f2b(v[3]);
        ((u16x4*)d)[i] = o;
    }
}

// ---------------------------------------------------------------------------
// GEMM: C[M][N] = A[M][K] @ W[N][K]^T  (bf16 in, f32 accum)
// m97 structure: 128x128 block tile, 4 waves of 64x64, BK=32,
// global_load_lds(16B) staging into linear [128][32] LDS tiles,
// ds_read_b128 fragment loads, mfma_f32_16x16x32_bf16.
//   A/B frag: row(col)=lane&15, k=8*(lane>>4)+i ; C/D: col=lane&15,
//   row=4*(lane>>4)+reg  [verified r2==r4 pipeline agreement]
// Staging map (linear LDS, wave-uniform base + lane*16):
//   callsite r in {0,1}, wave w: bytes [(r*4+w)*1024, +1024)
//   lane l -> tile row (r*4+w)*16 + l/4, col8 = (l&3)*8
// EPI 0: C[idx] = bf16(acc)                                  (k)
// EPI 1: C[idx] = bf16(acc * b2f(C[idx]))                    (kv, in-place)
// EPI 2: C[idx] = bf16(sigmoid(acc)*(lw.dec + wsum*b2f(C)))  (o, in-place)
// EPI 3: outf[idx] = acc (f32)                               (final output)
// ---------------------------------------------------------------------------
template <int EPI>
__global__ __launch_bounds__(256) void gemm_lds(
    const unsigned short* __restrict__ A,
    const unsigned short* __restrict__ Wt,
    unsigned short* C,
    float* __restrict__ outf,
    const float* __restrict__ lgw,
    const float* __restrict__ dec,
    int M, int N, int K)
{
    __shared__ unsigned short As[128 * 32];
    __shared__ unsigned short Bs[128 * 32];

    const int tid  = threadIdx.x;
    const int wid  = tid >> 6;
    const int lane = tid & 63;
    const int lr   = lane & 15;
    const int wr   = wid >> 1;           // wave row 0..1
    const int wc   = wid & 1;            // wave col 0..1
    const int row0 = blockIdx.x * 128;
    const int col0 = blockIdx.y * 128;

    // staging source addresses (per lane)
    const int srow = wid * 16 + (lane >> 2);   // callsite 0 row; +64 for callsite 1
    const int scol = (lane & 3) * 8;
    const unsigned short* gA0 = A  + (size_t)(row0 + srow) * K + scol;
    const unsigned short* gA1 = gA0 + (size_t)64 * K;
    const unsigned short* gB0 = Wt + (size_t)(col0 + srow) * K + scol;
    const unsigned short* gB1 = gB0 + (size_t)64 * K;
    // staging LDS dests (wave-uniform): 512 elems = 1KB per wave per callsite
    unsigned short* lA0 = As + wid * 512;
    unsigned short* lA1 = As + (4 + wid) * 512;
    unsigned short* lB0 = Bs + wid * 512;
    unsigned short* lB1 = Bs + (4 + wid) * 512;

    // fragment LDS read offsets (elements)
    const int kof = (lane >> 4) * 8;
    int aoff[4], boff[4];
#pragma unroll
    for (int i = 0; i < 4; ++i) {
        aoff[i] = (wr * 64 + i * 16 + lr) * 32 + kof;
        boff[i] = (wc * 64 + i * 16 + lr) * 32 + kof;
    }

    f32x4 acc[4][4];
#pragma unroll
    for (int i = 0; i < 4; ++i)
#pragma unroll
        for (int j = 0; j < 4; ++j)
            acc[i][j] = (f32x4){0.f, 0.f, 0.f, 0.f};

    for (int k0 = 0; k0 < K; k0 += 32) {
        __syncthreads();   // previous tile fully consumed before overwrite
        __builtin_amdgcn_global_load_lds(
            (const __attribute__((address_space(1))) unsigned int*)(gA0 + k0),
            (__attribute__((address_space(3))) unsigned int*)lA0, 16, 0, 0);
        __builtin_amdgcn_global_load_lds(
            (const __attribute__((address_space(1))) unsigned int*)(gA1 + k0),
            (__attribute__((address_space(3))) unsigned int*)lA1, 16, 0, 0);
        __builtin_amdgcn_global_load_lds(
            (const __attribute__((address_space(1))) unsigned int*)(gB0 + k0),
            (__attribute__((address_space(3))) unsigned int*)lB0, 16, 0, 0);
        __builtin_amdgcn_global_load_lds(
            (const __attribute__((address_space(1))) unsigned int*)(gB1 + k0),
            (__attribute__((address_space(3))) unsigned int*)lB1, 16, 0, 0);
        __syncthreads();   // drains vmcnt -> tile visible

        bf16x8 a[4], b[4];
#pragma unroll
        for (int i = 0; i < 4; ++i) a[i] = *(const bf16x8*)&As[aoff[i]];
#pragma unroll
        for (int i = 0; i < 4; ++i) b[i] = *(const bf16x8*)&Bs[boff[i]];
#pragma unroll
        for (int mi = 0; mi < 4; ++mi)
#pragma unroll
            for (int ni = 0; ni < 4; ++ni)
                acc[mi][ni] = __builtin_amdgcn_mfma_f32_16x16x32_bf16(
                    a[mi], b[ni], acc[mi][ni], 0, 0, 0);
    }

    const int orow0 = row0 + wr * 64;
    const int ocol0 = col0 + wc * 64;
    const int rbase = (lane >> 4) * 4;
    if (EPI == 0) {
#pragma unroll
        for (int mi = 0; mi < 4; ++mi)
#pragma unroll
            for (int j = 0; j < 4; ++j) {
                const size_t r = (size_t)(orow0 + mi * 16 + rbase + j);
#pragma unroll
                for (int ni = 0; ni < 4; ++ni)
                    C[r * N + (ocol0 + ni * 16 + lr)] = f2b(acc[mi][ni][j]);
            }
    } else if (EPI == 1) {
#pragma unroll
        for (int mi = 0; mi < 4; ++mi)
#pragma unroll
            for (int j = 0; j < 4; ++j) {
                const size_t r = (size_t)(orow0 + mi * 16 + rbase + j);
#pragma unroll
                for (int ni = 0; ni < 4; ++ni) {
                    const size_t idx = r * N + (ocol0 + ni * 16 + lr);
                    C[idx] = f2b(acc[mi][ni][j] * b2f(C[idx]));
                }
            }
    } else if (EPI == 2) {
        const int b = row0 >> 12;   // row/T_ (128-row blocks never straddle batch)
        float dcol[4][4];
#pragma unroll
        for (int ni = 0; ni < 4; ++ni)
#pragma unroll
            for (int d = 0; d < 4; ++d)
                dcol[ni][d] = dec[b * (D_ * H_) + d * H_ + (ocol0 + ni * 16 + lr)];
#pragma unroll
        for (int mi = 0; mi < 4; ++mi)
#pragma unroll
            for (int j = 0; j < 4; ++j) {
                const int r = orow0 + mi * 16 + rbase + j;
                const f32x4 lw = *(const f32x4*)(lgw + (size_t)r * 4);
                const float wsum = lw[0] + lw[1] + lw[2] + lw[3];
#pragma unroll
                for (int ni = 0; ni < 4; ++ni) {
                    const size_t idx = (size_t)r * N + (ocol0 + ni * 16 + lr);
                    const float rv = 1.0f / (1.0f + __expf(-acc[mi][ni][j]));
                    const float w  = lw[0] * dcol[ni][0] + lw[1] * dcol[ni][1]
                                   + lw[2] * dcol[ni][2] + lw[3] * dcol[ni][3]
                                   + wsum * b2f(C[idx]);
                    C[idx] = f2b(rv * w);
                }
            }
    } else {
#pragma unroll
        for (int mi = 0; mi < 4; ++mi)
#pragma unroll
            for (int j = 0; j < 4; ++j) {
                const size_t r = (size_t)(orow0 + mi * 16 + rbase + j);
#pragma unroll
                for (int ni = 0; ni < 4; ++ni)
                    outf[r * N + (ocol0 + ni * 16 + lr)] = acc[mi][ni][j];
            }
    }
}

// ---------------------------------------------------------------------------
// lgw[row][0..3] = softmax(x @ Wl^T + bl), one wave per row, f32.
// ---------------------------------------------------------------------------
__global__ __launch_bounds__(256) void logits_k(
    const float* __restrict__ X, const float* __restrict__ Wl,
    const float* __restrict__ bl, float* __restrict__ lgw)
{
    const int wid  = threadIdx.x >> 6;
    const int lane = threadIdx.x & 63;
    const int row  = blockIdx.x * 4 + wid;
    const float* xp = X + (size_t)row * H_;

    float acc[D_] = {0.f, 0.f, 0.f, 0.f};
    for (int h = lane * 4; h < H_; h += 256) {
        const f32x4 xv = *(const f32x4*)(xp + h);
#pragma unroll
        for (int d = 0; d < D_; ++d) {
            const f32x4 wv = *(const f32x4*)(Wl + d * H_ + h);
            acc[d] += xv[0] * wv[0] + xv[1] * wv[1] + xv[2] * wv[2] + xv[3] * wv[3];
        }
    }
#pragma unroll
    for (int off = 32; off; off >>= 1)
#pragma unroll
        for (int d = 0; d < D_; ++d) acc[d] += __shfl_xor(acc[d], off, 64);

    if (lane == 0) {
        float l[D_];
#pragma unroll
        for (int d = 0; d < D_; ++d) l[d] = acc[d] + bl[d];
        const float mx = fmaxf(fmaxf(l[0], l[1]), fmaxf(l[2], l[3]));
        float e[D_], s = 0.f;
#pragma unroll
        for (int d = 0; d < D_; ++d) { e[d] = __expf(l[d] - mx); s += e[d]; }
        const float inv = 1.0f / s;
        f32x4 o;
#pragma unroll
        for (int d = 0; d < D_; ++d) o[d] = e[d] * inv;
        *(f32x4*)(lgw + (size_t)row * 4) = o;
    }
}

// ---------------------------------------------------------------------------
__global__ void decstate_k(const float* __restrict__ state,
                           const float* __restrict__ tdm,
                           float* __restrict__ dec)
{
    const int i = blockIdx.x * blockDim.x + threadIdx.x;
    if (i >= B_ * D_ * H_) return;
    const int dh = i & (D_ * H_ - 1);
    dec[i] = state[i] * __expf(-__expf(tdm[dh]));
}

// ---------------------------------------------------------------------------
// new_state[b,d,h] = dec[b,d,h] + k_last*v_last, all-f32 exact path.
// ---------------------------------------------------------------------------
__global__ __launch_bounds__(256) void newstate_k(
    const float* __restrict__ X, const float* __restrict__ Wk,
    const float* __restrict__ Wv, const float* __restrict__ dec,
    float* __restrict__ out2)
{
    const int wid  = threadIdx.x >> 6;
    const int lane = threadIdx.x & 63;
    const int row  = blockIdx.x * 4 + wid;   // 0..B*H-1
    const int b    = row >> 10;
    const int h    = row & (H_ - 1);
    const float* xp = X + ((size_t)(b * T_ + (T_ - 1))) * H_;

    float ak = 0.f, av = 0.f;
    for (int j = lane * 4; j < H_; j += 256) {
        const f32x4 xv = *(const f32x4*)(xp + j);
        const f32x4 wk = *(const f32x4*)(Wk + (size_t)h * H_ + j);
        const f32x4 wv = *(const f32x4*)(Wv + (size_t)h * H_ + j);
        ak += xv[0]*wk[0] + xv[1]*wk[1] + xv[2]*wk[2] + xv[3]*wk[3];
        av += xv[0]*wv[0] + xv[1]*wv[1] + xv[2]*wv[2] + xv[3]*wv[3];
    }
#pragma unroll
    for (int off = 32; off; off >>= 1) {
        ak += __shfl_xor(ak, off, 64);
        av += __shfl_xor(av, off, 64);
    }
    if (lane == 0) {
        const float kv = ak * av;
#pragma unroll
        for (int d = 0; d < D_; ++d)
            out2[(size_t)(b * D_ + d) * H_ + h] = dec[(b * D_ + d) * H_ + h] + kv;
    }
}

// ---------------------------------------------------------------------------
extern "C" void kernel_launch(void* const* d_in, const int* in_sizes, int n_in,
                              void* d_out, int out_size, void* d_ws, size_t ws_size,
                              hipStream_t stream)
{
    const float* x   = (const float*)d_in[0];
    const float* st  = (const float*)d_in[1];
    const float* tdm = (const float*)d_in[2];
    const float* Wl  = (const float*)d_in[3];
    const float* bl  = (const float*)d_in[4];
    const float* Wv  = (const float*)d_in[5];
    const float* Wk  = (const float*)d_in[6];
    const float* Wr  = (const float*)d_in[7];
    const float* Wo  = (const float*)d_in[8];
    float* out = (float*)d_out;                    // f32 output

    char* ws = (char*)d_ws;
    unsigned short* buf  = (unsigned short*)(ws + WS_BUF);   // k -> kv -> o
    unsigned short* wk_b = (unsigned short*)(ws + WS_WK);
    unsigned short* wv_b = (unsigned short*)(ws + WS_WV);
    unsigned short* wr_b = (unsigned short*)(ws + WS_WR);
    unsigned short* wo_b = (unsigned short*)(ws + WS_WO);
    float* lgw = (float*)(ws + WS_LGW);
    float* dec = (float*)(ws + WS_DEC);

    // bf16 x scratch inside d_out's f32 output-0 region; final GEMM
    // fully overwrites it afterwards.
    unsigned short* xb = (unsigned short*)out;

    cvt_k<<<2048, 256, 0, stream>>>(x,  xb,   OUT_MAIN / 4);
    cvt_k<<<512,  256, 0, stream>>>(Wk, wk_b, (H_ * H_) / 4);
    cvt_k<<<512,  256, 0, stream>>>(Wv, wv_b, (H_ * H_) / 4);
    cvt_k<<<512,  256, 0, stream>>>(Wr, wr_b, (H_ * H_) / 4);
    cvt_k<<<512,  256, 0, stream>>>(Wo, wo_b, (H_ * H_) / 4);

    const dim3 g(M_ / 128, H_ / 128), blk(256);

    // buf = k
    hipLaunchKernelGGL((gemm_lds<0>), g, blk, 0, stream, xb, wk_b, buf,
                       (float*)nullptr, (const float*)nullptr, (const float*)nullptr,
                       M_, H_, H_);
    // buf = kv
    hipLaunchKernelGGL((gemm_lds<1>), g, blk, 0, stream, xb, wv_b, buf,
                       (float*)nullptr, (const float*)nullptr, (const float*)nullptr,
                       M_, H_, H_);
    logits_k<<<M_ / 4, 256, 0, stream>>>(x, Wl, bl, lgw);
    decstate_k<<<(B_ * D_ * H_ + 255) / 256, 256, 0, stream>>>(st, tdm, dec);
    // new_state (f32 exact, independent of bf16 buffers)
    newstate_k<<<(B_ * H_) / 4, 256, 0, stream>>>(x, Wk, Wv, dec, out + OUT_MAIN);
    // buf = o = sigmoid(x@Wr^T) * (lw.dec + wsum*kv)
    hipLaunchKernelGGL((gemm_lds<2>), g, blk, 0, stream, xb, wr_b, buf,
                       (float*)nullptr, (const float*)lgw, (const float*)dec,
                       M_, H_, H_);
    // out = f32(o @ Wo^T)
    hipLaunchKernelGGL((gemm_lds<3>), g, blk, 0, stream, buf, wo_b, (unsigned short*)nullptr,
                       out, (const float*)nullptr, (const float*)nullptr,
                       M_, H_, H_);
}

// Round 7
// 274.753 us; speedup vs baseline: 1.9733x; 1.0465x over previous
//
#include <hip/hip_runtime.h>

// HierarchicalTimeAttention  B=4, T=4096, H=1024, D=4
// R7: 2-phase prefetch GEMM (T3-minimal): double-buffered LDS, issue next
// K-tile's global_load_lds BEFORE computing current tile, one raw s_barrier
// + counted vmcnt(0) per step (no __syncthreads full-drain).
// R6 baseline: GEMM 75.6us, MfmaUtil 18%, exposed load latency per K-step.
#define B_ 4
#define T_ 4096
#define H_ 1024
#define D_ 4
#define M_ (B_ * T_)          // 16384
#define OUT_MAIN (M_ * H_)    // 16,777,216 (f32 elements)

// ws (bytes), total ~40.3MB (ws_size >= 67.4MB verified in r4):
#define WS_BUF  0UL           // bf16 [M][H]: k -> kv -> o   (32MB)
#define WS_WK   33554432UL    // bf16 Wk,Wv,Wr,Wo contiguous [4][H][H] (8MB)
#define WS_LGW  41943040UL    // f32 softmax weights [M][4] (256KB)
#define WS_DEC  42205184UL    // f32 decayed_state0 [B][D][H] (64KB)

typedef __bf16 bf16x8 __attribute__((ext_vector_type(8)));
typedef unsigned short u16x4 __attribute__((ext_vector_type(4)));
typedef float f32x4 __attribute__((ext_vector_type(4)));

__device__ __forceinline__ float b2f(unsigned short u) {
    union { unsigned int i; float f; } c;
    c.i = ((unsigned int)u) << 16;
    return c.f;
}
__device__ __forceinline__ unsigned short f2b(float f) {
    union { float f; unsigned int i; } c;
    c.f = f;
    unsigned int x = c.i;
    unsigned int r = (x + 0x7FFFu + ((x >> 16) & 1u)) >> 16;  // RNE
    return (unsigned short)r;
}

// ---------------------------------------------------------------------------
// f32 -> bf16 conversions
// ---------------------------------------------------------------------------
__global__ __launch_bounds__(256) void cvt_k(const float* __restrict__ s,
                                             unsigned short* __restrict__ d, int n4)
{
    int i = blockIdx.x * 256 + threadIdx.x;
    const int str = gridDim.x * 256;
    for (; i < n4; i += str) {
        const f32x4 v = ((const f32x4*)s)[i];
        u16x4 o;
        o[0] = f2b(v[0]); o[1] = f2b(v[1]); o[2] = f2b(v[2]); o[3] = f2b(v[3]);
        ((u16x4*)d)[i] = o;
    }
}

// 4 weight matrices in one dispatch: grid (1024, 4), dst contiguous [4][H][H]
__global__ __launch_bounds__(256) void cvtw_k(
    const float* __restrict__ s0, const float* __restrict__ s1,
    const float* __restrict__ s2, const float* __restrict__ s3,
    unsigned short* __restrict__ d)
{
    const int w = blockIdx.y;
    const float* s = (w == 0) ? s0 : (w == 1) ? s1 : (w == 2) ? s2 : s3;
    const int i = blockIdx.x * 256 + threadIdx.x;   // 0..262143 (f32x4 units)
    const f32x4 v = ((const f32x4*)s)[i];
    u16x4 o;
    o[0] = f2b(v[0]); o[1] = f2b(v[1]); o[2] = f2b(v[2]); o[3] = f2b(v[3]);
    ((u16x4*)(d + (size_t)w * (H_ * H_)))[i] = o;
}

// ---------------------------------------------------------------------------
// GEMM: C[16384][1024] = A[16384][1024] @ W[1024][1024]^T  (bf16 in, f32 acc)
// 2-phase: 128x128 tile, 4 waves of 64x64, BK=32, double-buffered LDS,
// prefetch next K-tile via global_load_lds(16B) BEFORE computing current,
// then s_waitcnt vmcnt(0) + raw s_barrier (one barrier per K-step).
//   A/B frag: row(col)=lane&15, k=8*(lane>>4)+i ; C/D: col=lane&15,
//   row=4*(lane>>4)+reg  [verified r2==r4 pipeline agreement]
// EPI 0: C = bf16(acc)        EPI 1: C = bf16(acc * C)   (in-place)
// EPI 2: C = bf16(sigmoid(acc)*(lw.dec + wsum*C))        (in-place)
// EPI 3: outf = acc (f32)
// ---------------------------------------------------------------------------
template <int EPI>
__global__ __launch_bounds__(256) void gemm2p(
    const unsigned short* __restrict__ A,
    const unsigned short* __restrict__ Wt,
    unsigned short* C,
    float* __restrict__ outf,
    const float* __restrict__ lgw,
    const float* __restrict__ dec)
{
    __shared__ unsigned short As[2 * 128 * 32];
    __shared__ unsigned short Bs[2 * 128 * 32];

    const int tid  = threadIdx.x;
    const int wid  = tid >> 6;
    const int lane = tid & 63;
    const int lr   = lane & 15;
    const int wr   = wid >> 1;
    const int wc   = wid & 1;
    const int row0 = blockIdx.x * 128;
    const int col0 = blockIdx.y * 128;

    // staging: callsite r in {0,1}, wave w -> tile rows [(r*4+w)*16, +16)
    // lane l -> row +(l>>2), col (l&3)*8 ; LDS linear [128][32]
    const int srow = wid * 16 + (lane >> 2);
    const int scol = (lane & 3) * 8;
    const unsigned short* gA0 = A  + (size_t)(row0 + srow) * 1024 + scol;
    const unsigned short* gB0 = Wt + (size_t)(col0 + srow) * 1024 + scol;
    const int sOf0 = wid * 512;          // wave-uniform LDS elem offsets
    const int sOf1 = (4 + wid) * 512;

#define STAGE(bufo, kk)                                                          \
    do {                                                                         \
        __builtin_amdgcn_global_load_lds(                                        \
            (const __attribute__((address_space(1))) unsigned int*)(gA0 + (kk)), \
            (__attribute__((address_space(3))) unsigned int*)(As + (bufo) + sOf0), 16, 0, 0); \
        __builtin_amdgcn_global_load_lds(                                        \
            (const __attribute__((address_space(1))) unsigned int*)(gA0 + 64 * 1024 + (kk)), \
            (__attribute__((address_space(3))) unsigned int*)(As + (bufo) + sOf1), 16, 0, 0); \
        __builtin_amdgcn_global_load_lds(                                        \
            (const __attribute__((address_space(1))) unsigned int*)(gB0 + (kk)), \
            (__attribute__((address_space(3))) unsigned int*)(Bs + (bufo) + sOf0), 16, 0, 0); \
        __builtin_amdgcn_global_load_lds(                                        \
            (const __attribute__((address_space(1))) unsigned int*)(gB0 + 64 * 1024 + (kk)), \
            (__attribute__((address_space(3))) unsigned int*)(Bs + (bufo) + sOf1), 16, 0, 0); \
    } while (0)

    // fragment LDS read offsets (elements within one buffer)
    const int kof = (lane >> 4) * 8;
    int aoff[4], boff[4];
#pragma unroll
    for (int i = 0; i < 4; ++i) {
        aoff[i] = (wr * 64 + i * 16 + lr) * 32 + kof;
        boff[i] = (wc * 64 + i * 16 + lr) * 32 + kof;
    }

    f32x4 acc[4][4];
#pragma unroll
    for (int i = 0; i < 4; ++i)
#pragma unroll
        for (int j = 0; j < 4; ++j)
            acc[i][j] = (f32x4){0.f, 0.f, 0.f, 0.f};

    // prologue: stage tile 0 into buffer 0
    STAGE(0, 0);
    asm volatile("s_waitcnt vmcnt(0)" ::: "memory");
    __builtin_amdgcn_s_barrier();

    int curo = 0;
    for (int t = 0; t < 32; ++t) {
        const int nxto = curo ^ 4096;
        if (t < 31) STAGE(nxto, (t + 1) * 32);   // prefetch BEFORE compute

        bf16x8 a[4], b[4];
#pragma unroll
        for (int i = 0; i < 4; ++i) a[i] = *(const bf16x8*)&As[curo + aoff[i]];
#pragma unroll
        for (int i = 0; i < 4; ++i) b[i] = *(const bf16x8*)&Bs[curo + boff[i]];
#pragma unroll
        for (int mi = 0; mi < 4; ++mi)
#pragma unroll
            for (int ni = 0; ni < 4; ++ni)
                acc[mi][ni] = __builtin_amdgcn_mfma_f32_16x16x32_bf16(
                    a[mi], b[ni], acc[mi][ni], 0, 0, 0);

        if (t < 31) {
            asm volatile("s_waitcnt vmcnt(0)" ::: "memory");  // prefetch landed
            __builtin_amdgcn_s_barrier();                     // all waves done reading curo
            curo = nxto;
        }
    }
#undef STAGE

    const int orow0 = row0 + wr * 64;
    const int ocol0 = col0 + wc * 64;
    const int rbase = (lane >> 4) * 4;
    if (EPI == 0) {
#pragma unroll
        for (int mi = 0; mi < 4; ++mi)
#pragma unroll
            for (int j = 0; j < 4; ++j) {
                const size_t r = (size_t)(orow0 + mi * 16 + rbase + j);
#pragma unroll
                for (int ni = 0; ni < 4; ++ni)
                    C[r * 1024 + (ocol0 + ni * 16 + lr)] = f2b(acc[mi][ni][j]);
            }
    } else if (EPI == 1) {
#pragma unroll
        for (int mi = 0; mi < 4; ++mi)
#pragma unroll
            for (int j = 0; j < 4; ++j) {
                const size_t r = (size_t)(orow0 + mi * 16 + rbase + j);
#pragma unroll
                for (int ni = 0; ni < 4; ++ni) {
                    const size_t idx = r * 1024 + (ocol0 + ni * 16 + lr);
                    C[idx] = f2b(acc[mi][ni][j] * b2f(C[idx]));
                }
            }
    } else if (EPI == 2) {
        const int b = row0 >> 12;   // row/T_ (128-row blocks never straddle batch)
        float dcol[4][4];
#pragma unroll
        for (int ni = 0; ni < 4; ++ni)
#pragma unroll
            for (int d = 0; d < 4; ++d)
                dcol[ni][d] = dec[b * (D_ * H_) + d * H_ + (ocol0 + ni * 16 + lr)];
#pragma unroll
        for (int mi = 0; mi < 4; ++mi)
#pragma unroll
            for (int j = 0; j < 4; ++j) {
                const int r = orow0 + mi * 16 + rbase + j;
                const f32x4 lw = *(const f32x4*)(lgw + (size_t)r * 4);
                const float wsum = lw[0] + lw[1] + lw[2] + lw[3];
#pragma unroll
                for (int ni = 0; ni < 4; ++ni) {
                    const size_t idx = (size_t)r * 1024 + (ocol0 + ni * 16 + lr);
                    const float rv = 1.0f / (1.0f + __expf(-acc[mi][ni][j]));
                    const float w  = lw[0] * dcol[ni][0] + lw[1] * dcol[ni][1]
                                   + lw[2] * dcol[ni][2] + lw[3] * dcol[ni][3]
                                   + wsum * b2f(C[idx]);
                    C[idx] = f2b(rv * w);
                }
            }
    } else {
#pragma unroll
        for (int mi = 0; mi < 4; ++mi)
#pragma unroll
            for (int j = 0; j < 4; ++j) {
                const size_t r = (size_t)(orow0 + mi * 16 + rbase + j);
#pragma unroll
                for (int ni = 0; ni < 4; ++ni)
                    outf[r * 1024 + (ocol0 + ni * 16 + lr)] = acc[mi][ni][j];
            }
    }
}

// ---------------------------------------------------------------------------
// lgw[row][0..3] = softmax(x @ Wl^T + bl), one wave per row, f32.
// ---------------------------------------------------------------------------
__global__ __launch_bounds__(256) void logits_k(
    const float* __restrict__ X, const float* __restrict__ Wl,
    const float* __restrict__ bl, float* __restrict__ lgw)
{
    const int wid  = threadIdx.x >> 6;
    const int lane = threadIdx.x & 63;
    const int row  = blockIdx.x * 4 + wid;
    const float* xp = X + (size_t)row * H_;

    float acc[D_] = {0.f, 0.f, 0.f, 0.f};
    for (int h = lane * 4; h < H_; h += 256) {
        const f32x4 xv = *(const f32x4*)(xp + h);
#pragma unroll
        for (int d = 0; d < D_; ++d) {
            const f32x4 wv = *(const f32x4*)(Wl + d * H_ + h);
            acc[d] += xv[0] * wv[0] + xv[1] * wv[1] + xv[2] * wv[2] + xv[3] * wv[3];
        }
    }
#pragma unroll
    for (int off = 32; off; off >>= 1)
#pragma unroll
        for (int d = 0; d < D_; ++d) acc[d] += __shfl_xor(acc[d], off, 64);

    if (lane == 0) {
        float l[D_];
#pragma unroll
        for (int d = 0; d < D_; ++d) l[d] = acc[d] + bl[d];
        const float mx = fmaxf(fmaxf(l[0], l[1]), fmaxf(l[2], l[3]));
        float e[D_], s = 0.f;
#pragma unroll
        for (int d = 0; d < D_; ++d) { e[d] = __expf(l[d] - mx); s += e[d]; }
        const float inv = 1.0f / s;
        f32x4 o;
#pragma unroll
        for (int d = 0; d < D_; ++d) o[d] = e[d] * inv;
        *(f32x4*)(lgw + (size_t)row * 4) = o;
    }
}

// ---------------------------------------------------------------------------
__global__ void decstate_k(const float* __restrict__ state,
                           const float* __restrict__ tdm,
                           float* __restrict__ dec)
{
    const int i = blockIdx.x * blockDim.x + threadIdx.x;
    if (i >= B_ * D_ * H_) return;
    const int dh = i & (D_ * H_ - 1);
    dec[i] = state[i] * __expf(-__expf(tdm[dh]));
}

// ---------------------------------------------------------------------------
// new_state[b,d,h] = dec[b,d,h] + k_last*v_last, all-f32 exact path.
// ---------------------------------------------------------------------------
__global__ __launch_bounds__(256) void newstate_k(
    const float* __restrict__ X, const float* __restrict__ Wk,
    const float* __restrict__ Wv, const float* __restrict__ dec,
    float* __restrict__ out2)
{
    const int wid  = threadIdx.x >> 6;
    const int lane = threadIdx.x & 63;
    const int row  = blockIdx.x * 4 + wid;   // 0..B*H-1
    const int b    = row >> 10;
    const int h    = row & (H_ - 1);
    const float* xp = X + ((size_t)(b * T_ + (T_ - 1))) * H_;

    float ak = 0.f, av = 0.f;
    for (int j = lane * 4; j < H_; j += 256) {
        const f32x4 xv = *(const f32x4*)(xp + j);
        const f32x4 wk = *(const f32x4*)(Wk + (size_t)h * H_ + j);
        const f32x4 wv = *(const f32x4*)(Wv + (size_t)h * H_ + j);
        ak += xv[0]*wk[0] + xv[1]*wk[1] + xv[2]*wk[2] + xv[3]*wk[3];
        av += xv[0]*wv[0] + xv[1]*wv[1] + xv[2]*wv[2] + xv[3]*wv[3];
    }
#pragma unroll
    for (int off = 32; off; off >>= 1) {
        ak += __shfl_xor(ak, off, 64);
        av += __shfl_xor(av, off, 64);
    }
    if (lane == 0) {
        const float kv = ak * av;
#pragma unroll
        for (int d = 0; d < D_; ++d)
            out2[(size_t)(b * D_ + d) * H_ + h] = dec[(b * D_ + d) * H_ + h] + kv;
    }
}

// ---------------------------------------------------------------------------
extern "C" void kernel_launch(void* const* d_in, const int* in_sizes, int n_in,
                              void* d_out, int out_size, void* d_ws, size_t ws_size,
                              hipStream_t stream)
{
    const float* x   = (const float*)d_in[0];
    const float* st  = (const float*)d_in[1];
    const float* tdm = (const float*)d_in[2];
    const float* Wl  = (const float*)d_in[3];
    const float* bl  = (const float*)d_in[4];
    const float* Wv  = (const float*)d_in[5];
    const float* Wk  = (const float*)d_in[6];
    const float* Wr  = (const float*)d_in[7];
    const float* Wo  = (const float*)d_in[8];
    float* out = (float*)d_out;                    // f32 output

    char* ws = (char*)d_ws;
    unsigned short* buf  = (unsigned short*)(ws + WS_BUF);   // k -> kv -> o
    unsigned short* wk_b = (unsigned short*)(ws + WS_WK);    // [4][H][H]: k,v,r,o
    unsigned short* wv_b = wk_b + 1 * (H_ * H_);
    unsigned short* wr_b = wk_b + 2 * (H_ * H_);
    unsigned short* wo_b = wk_b + 3 * (H_ * H_);
    float* lgw = (float*)(ws + WS_LGW);
    float* dec = (float*)(ws + WS_DEC);

    // bf16 x scratch inside d_out's f32 output-0 region; final GEMM
    // fully overwrites it afterwards.
    unsigned short* xb = (unsigned short*)out;

    // small f32 kernels (depend only on raw inputs)
    logits_k<<<M_ / 4, 256, 0, stream>>>(x, Wl, bl, lgw);
    decstate_k<<<(B_ * D_ * H_ + 255) / 256, 256, 0, stream>>>(st, tdm, dec);
    newstate_k<<<(B_ * H_) / 4, 256, 0, stream>>>(x, Wk, Wv, dec, out + OUT_MAIN);

    // conversions
    cvt_k<<<2048, 256, 0, stream>>>(x, xb, OUT_MAIN / 4);
    cvtw_k<<<dim3(1024, 4), 256, 0, stream>>>(Wk, Wv, Wr, Wo, wk_b);

    const dim3 g(M_ / 128, H_ / 128), blk(256);

    // buf = k
    hipLaunchKernelGGL((gemm2p<0>), g, blk, 0, stream, xb, wk_b, buf,
                       (float*)nullptr, (const float*)nullptr, (const float*)nullptr);
    // buf = kv
    hipLaunchKernelGGL((gemm2p<1>), g, blk, 0, stream, xb, wv_b, buf,
                       (float*)nullptr, (const float*)nullptr, (const float*)nullptr);
    // buf = o = sigmoid(x@Wr^T) * (lw.dec + wsum*kv)
    hipLaunchKernelGGL((gemm2p<2>), g, blk, 0, stream, xb, wr_b, buf,
                       (float*)nullptr, (const float*)lgw, (const float*)dec);
    // out = f32(o @ Wo^T)
    hipLaunchKernelGGL((gemm2p<3>), g, blk, 0, stream, buf, wo_b, (unsigned short*)nullptr,
                       out, (const float*)nullptr, (const float*)nullptr);
}

// Round 8
// 199.356 us; speedup vs baseline: 2.7195x; 1.3782x over previous
//
#include <hip/hip_runtime.h>

// HierarchicalTimeAttention  B=4, T=4096, H=1024, D=4
// R8: 8-phase-schedule GEMM (T3+T4+T2+T5): 256x256 tile, BK=64, 8 waves,
// 128KB dbuf LDS, 4 phases/K-step {ds_read || stage-issue || bar ||
// setprio+MFMA || bar}, XOR-swizzled LDS (inverse-swizzled global source,
// swizzled read), vmcnt(0) once per K-step (stages issued 2-3 phases early).
// R7 baseline: GEMM 74.4us, MfmaUtil 19%, 2-phase drain-bound (m233 regime).
#define B_ 4
#define T_ 4096
#define H_ 1024
#define D_ 4
#define M_ (B_ * T_)          // 16384
#define OUT_MAIN (M_ * H_)    // 16,777,216 (f32 elements)

// ws (bytes), total ~40.3MB:
#define WS_BUF  0UL           // bf16 [M][H]: k -> kv -> o   (32MB)
#define WS_WK   33554432UL    // bf16 Wk,Wv,Wr,Wo contiguous [4][H][H] (8MB)
#define WS_LGW  41943040UL    // f32 softmax weights [M][4] (256KB)
#define WS_DEC  42205184UL    // f32 decayed_state0 [B][D][H] (64KB)

typedef __bf16 bf16x8 __attribute__((ext_vector_type(8)));
typedef unsigned short u16x4 __attribute__((ext_vector_type(4)));
typedef float f32x4 __attribute__((ext_vector_type(4)));

__device__ __forceinline__ float b2f(unsigned short u) {
    union { unsigned int i; float f; } c;
    c.i = ((unsigned int)u) << 16;
    return c.f;
}
__device__ __forceinline__ unsigned short f2b(float f) {
    union { float f; unsigned int i; } c;
    c.f = f;
    unsigned int x = c.i;
    unsigned int r = (x + 0x7FFFu + ((x >> 16) & 1u)) >> 16;  // RNE
    return (unsigned short)r;
}

#define BAR()  asm volatile("s_barrier" ::: "memory")
#define VMCNT0() asm volatile("s_waitcnt vmcnt(0)" ::: "memory")
#define GLLDS(gsrc, ldst)                                                     \
    __builtin_amdgcn_global_load_lds(                                         \
        (const __attribute__((address_space(1))) unsigned int*)(gsrc),        \
        (__attribute__((address_space(3))) unsigned int*)(ldst), 16, 0, 0)

// ---------------------------------------------------------------------------
// f32 -> bf16 conversions
// ---------------------------------------------------------------------------
__global__ __launch_bounds__(256) void cvt_k(const float* __restrict__ s,
                                             unsigned short* __restrict__ d, int n4)
{
    int i = blockIdx.x * 256 + threadIdx.x;
    const int str = gridDim.x * 256;
    for (; i < n4; i += str) {
        const f32x4 v = ((const f32x4*)s)[i];
        u16x4 o;
        o[0] = f2b(v[0]); o[1] = f2b(v[1]); o[2] = f2b(v[2]); o[3] = f2b(v[3]);
        ((u16x4*)d)[i] = o;
    }
}

// 4 weight matrices in one dispatch: grid (1024, 4), dst contiguous [4][H][H]
__global__ __launch_bounds__(256) void cvtw_k(
    const float* __restrict__ s0, const float* __restrict__ s1,
    const float* __restrict__ s2, const float* __restrict__ s3,
    unsigned short* __restrict__ d)
{
    const int w = blockIdx.y;
    const float* s = (w == 0) ? s0 : (w == 1) ? s1 : (w == 2) ? s2 : s3;
    const int i = blockIdx.x * 256 + threadIdx.x;
    const f32x4 v = ((const f32x4*)s)[i];
    u16x4 o;
    o[0] = f2b(v[0]); o[1] = f2b(v[1]); o[2] = f2b(v[2]); o[3] = f2b(v[3]);
    ((u16x4*)(d + (size_t)w * (H_ * H_)))[i] = o;
}

// ---------------------------------------------------------------------------
// GEMM: C[16384][1024] = A[16384][1024] @ W[1024][1024]^T  (bf16, f32 acc)
// 256x256 tile, 8 waves (2Mx4N, 128x64 per wave), BK=64, dbuf LDS 128KB.
// LDS layout per half-buffer: [256 rows][8 granules of 16B], granule
// SWIZZLE: phys_g = logical_g ^ (row&7). Staged via global_load_lds with
// inverse-swizzled per-lane GLOBAL source (linear LDS dest), read back with
// the same XOR (rule #21: both-sides). Kills the 16-way stride-128B conflict.
// Per K-step: 4 phases {ds_read subtile; stage-issue; bar; prio1; 16 MFMA;
// prio0; bar}; quadrant order (r0c01, r0c23, r1c23, r1c01); stages for step
// t+1 issued phases 1-3; single vmcnt(0) at end of step (T4: issue-to-drain
// distance ~2-3 phases of MFMA covers L2/HBM latency).
//   A/B frag: row(col)=lane&15, k=8*(lane>>4)+i ; C/D: col=lane&15,
//   row=4*(lane>>4)+reg  [verified r2==r4 pipeline agreement]
// EPI 0: C = bf16(acc)        EPI 1: C = bf16(acc * C)   (in-place)
// EPI 2: C = bf16(sigmoid(acc)*(lw.dec + wsum*C))        (in-place)
// EPI 3: outf = acc (f32)
// ---------------------------------------------------------------------------
template <int EPI>
__global__ __launch_bounds__(512, 2) void gemm8p(
    const unsigned short* __restrict__ A,
    const unsigned short* __restrict__ Wt,
    unsigned short* C,
    float* __restrict__ outf,
    const float* __restrict__ lgw,
    const float* __restrict__ dec)
{
    __shared__ __align__(16) unsigned short As[2 * 256 * 64];
    __shared__ __align__(16) unsigned short Bs[2 * 256 * 64];

    const int tid  = threadIdx.x;
    const int wid  = tid >> 6;        // 0..7
    const int lane = tid & 63;
    const int l15  = lane & 15;
    const int l7   = lane & 7;
    const int wrow = wid >> 2;        // 0..1  (128-row half)
    const int wcol = wid & 3;         // 0..3  (64-col quarter)
    const int brow = blockIdx.x * 256;
    const int bcol = blockIdx.y * 256;

    // --- staging precompute: 4 calls per matrix, 1 granule(16B)/thread/call
    // linear LDS granule G = i*512 + tid  ->  (row = G>>3, phys cg = G&7)
    // data for phys cg comes from logical cg_src = (G&7) ^ (row&7)
    int offA[4], offB[4], dst[4];
#pragma unroll
    for (int i = 0; i < 4; ++i) {
        const int G   = i * 512 + tid;
        const int row = G >> 3;
        const int cg  = (G & 7) ^ (row & 7);
        offA[i] = (brow + row) * 1024 + cg * 8;
        offB[i] = (bcol + row) * 1024 + cg * 8;
        dst[i]  = G * 8;              // element offset in half-buffer
    }

    // --- ds_read bases: frag (row16-block, ks) -> row*64 + (g ^ l7)*8
    int aB[8], bB[4], gx[2];
#pragma unroll
    for (int ks = 0; ks < 2; ++ks) gx[ks] = ((ks * 4 + (lane >> 4)) ^ l7) * 8;
#pragma unroll
    for (int mi = 0; mi < 8; ++mi) aB[mi] = (wrow * 128 + mi * 16 + l15) * 64;
#pragma unroll
    for (int ni = 0; ni < 4; ++ni) bB[ni] = (wcol * 64 + ni * 16 + l15) * 64;

    f32x4 acc[8][4];
#pragma unroll
    for (int i = 0; i < 8; ++i)
#pragma unroll
        for (int j = 0; j < 4; ++j)
            acc[i][j] = (f32x4){0.f, 0.f, 0.f, 0.f};

    // --- prologue: stage K-step 0 into buffer 0
#pragma unroll
    for (int i = 0; i < 4; ++i) {
        GLLDS(A  + offA[i], As + dst[i]);
        GLLDS(Wt + offB[i], Bs + dst[i]);
    }
    VMCNT0();
    BAR();

#pragma unroll 1
    for (int t = 0; t < 16; ++t) {
        const int cur = (t & 1) * 16384;
        const int nxt = 16384 - cur;
        const int kk  = (t + 1) * 64;
        const bool st = (t < 15);
        bf16x8 aR[4][2], bR[4][2];

        // ---- P1: read a(r0: mi0-3) + b(c0-1); stage A0,A1,B0
#pragma unroll
        for (int mi = 0; mi < 4; ++mi)
#pragma unroll
            for (int ks = 0; ks < 2; ++ks)
                aR[mi][ks] = *(const bf16x8*)&As[cur + aB[mi] + gx[ks]];
#pragma unroll
        for (int ni = 0; ni < 2; ++ni)
#pragma unroll
            for (int ks = 0; ks < 2; ++ks)
                bR[ni][ks] = *(const bf16x8*)&Bs[cur + bB[ni] + gx[ks]];
        if (st) {
            GLLDS(A  + offA[0] + kk, As + nxt + dst[0]);
            GLLDS(A  + offA[1] + kk, As + nxt + dst[1]);
            GLLDS(Wt + offB[0] + kk, Bs + nxt + dst[0]);
        }
        BAR();
        __builtin_amdgcn_s_setprio(1);
#pragma unroll
        for (int mi = 0; mi < 4; ++mi)
#pragma unroll
            for (int ni = 0; ni < 2; ++ni)
#pragma unroll
                for (int ks = 0; ks < 2; ++ks)
                    acc[mi][ni] = __builtin_amdgcn_mfma_f32_16x16x32_bf16(
                        aR[mi][ks], bR[ni][ks], acc[mi][ni], 0, 0, 0);
        __builtin_amdgcn_s_setprio(0);
        BAR();

        // ---- P2: read b(c2-3); stage A2,A3,B1
#pragma unroll
        for (int ni = 2; ni < 4; ++ni)
#pragma unroll
            for (int ks = 0; ks < 2; ++ks)
                bR[ni][ks] = *(const bf16x8*)&Bs[cur + bB[ni] + gx[ks]];
        if (st) {
            GLLDS(A  + offA[2] + kk, As + nxt + dst[2]);
            GLLDS(A  + offA[3] + kk, As + nxt + dst[3]);
            GLLDS(Wt + offB[1] + kk, Bs + nxt + dst[1]);
        }
        BAR();
        __builtin_amdgcn_s_setprio(1);
#pragma unroll
        for (int mi = 0; mi < 4; ++mi)
#pragma unroll
            for (int ni = 2; ni < 4; ++ni)
#pragma unroll
                for (int ks = 0; ks < 2; ++ks)
                    acc[mi][ni] = __builtin_amdgcn_mfma_f32_16x16x32_bf16(
                        aR[mi][ks], bR[ni][ks], acc[mi][ni], 0, 0, 0);
        __builtin_amdgcn_s_setprio(0);
        BAR();

        // ---- P3: read a(r1: mi4-7, reuse aR slots); stage B2,B3
#pragma unroll
        for (int mi = 0; mi < 4; ++mi)
#pragma unroll
            for (int ks = 0; ks < 2; ++ks)
                aR[mi][ks] = *(const bf16x8*)&As[cur + aB[4 + mi] + gx[ks]];
        if (st) {
            GLLDS(Wt + offB[2] + kk, Bs + nxt + dst[2]);
            GLLDS(Wt + offB[3] + kk, Bs + nxt + dst[3]);
        }
        BAR();
        __builtin_amdgcn_s_setprio(1);
#pragma unroll
        for (int mi = 0; mi < 4; ++mi)
#pragma unroll
            for (int ni = 2; ni < 4; ++ni)
#pragma unroll
                for (int ks = 0; ks < 2; ++ks)
                    acc[4 + mi][ni] = __builtin_amdgcn_mfma_f32_16x16x32_bf16(
                        aR[mi][ks], bR[ni][ks], acc[4 + mi][ni], 0, 0, 0);
        __builtin_amdgcn_s_setprio(0);
        BAR();

        // ---- P4: MFMA r1 x c0-1; end-of-step drain + swap barrier
        __builtin_amdgcn_s_setprio(1);
#pragma unroll
        for (int mi = 0; mi < 4; ++mi)
#pragma unroll
            for (int ni = 0; ni < 2; ++ni)
#pragma unroll
                for (int ks = 0; ks < 2; ++ks)
                    acc[4 + mi][ni] = __builtin_amdgcn_mfma_f32_16x16x32_bf16(
                        aR[mi][ks], bR[ni][ks], acc[4 + mi][ni], 0, 0, 0);
        __builtin_amdgcn_s_setprio(0);
        VMCNT0();   // t+1 stages (issued P1-P3) have landed
        BAR();      // all waves done reading cur + see staged nxt
    }

    // ---- epilogue
    const int orow0 = brow + wrow * 128;
    const int ocol0 = bcol + wcol * 64;
    const int rbase = (lane >> 4) * 4;
    if (EPI == 0) {
#pragma unroll
        for (int mi = 0; mi < 8; ++mi)
#pragma unroll
            for (int j = 0; j < 4; ++j) {
                const size_t r = (size_t)(orow0 + mi * 16 + rbase + j);
#pragma unroll
                for (int ni = 0; ni < 4; ++ni)
                    C[r * 1024 + (ocol0 + ni * 16 + l15)] = f2b(acc[mi][ni][j]);
            }
    } else if (EPI == 1) {
#pragma unroll
        for (int mi = 0; mi < 8; ++mi)
#pragma unroll
            for (int j = 0; j < 4; ++j) {
                const size_t r = (size_t)(orow0 + mi * 16 + rbase + j);
#pragma unroll
                for (int ni = 0; ni < 4; ++ni) {
                    const size_t idx = r * 1024 + (ocol0 + ni * 16 + l15);
                    C[idx] = f2b(acc[mi][ni][j] * b2f(C[idx]));
                }
            }
    } else if (EPI == 2) {
        const int b = brow >> 12;   // 256-row blocks never straddle a batch
        float dcol[4][4];
#pragma unroll
        for (int ni = 0; ni < 4; ++ni)
#pragma unroll
            for (int d = 0; d < 4; ++d)
                dcol[ni][d] = dec[b * (D_ * H_) + d * H_ + (ocol0 + ni * 16 + l15)];
#pragma unroll
        for (int mi = 0; mi < 8; ++mi)
#pragma unroll
            for (int j = 0; j < 4; ++j) {
                const int r = orow0 + mi * 16 + rbase + j;
                const f32x4 lw = *(const f32x4*)(lgw + (size_t)r * 4);
                const float wsum = lw[0] + lw[1] + lw[2] + lw[3];
#pragma unroll
                for (int ni = 0; ni < 4; ++ni) {
                    const size_t idx = (size_t)r * 1024 + (ocol0 + ni * 16 + l15);
                    const float rv = 1.0f / (1.0f + __expf(-acc[mi][ni][j]));
                    const float w  = lw[0] * dcol[ni][0] + lw[1] * dcol[ni][1]
                                   + lw[2] * dcol[ni][2] + lw[3] * dcol[ni][3]
                                   + wsum * b2f(C[idx]);
                    C[idx] = f2b(rv * w);
                }
            }
    } else {
#pragma unroll
        for (int mi = 0; mi < 8; ++mi)
#pragma unroll
            for (int j = 0; j < 4; ++j) {
                const size_t r = (size_t)(orow0 + mi * 16 + rbase + j);
#pragma unroll
                for (int ni = 0; ni < 4; ++ni)
                    outf[r * 1024 + (ocol0 + ni * 16 + l15)] = acc[mi][ni][j];
            }
    }
}

// ---------------------------------------------------------------------------
// lgw[row][0..3] = softmax(x @ Wl^T + bl), one wave per row, f32.
// ---------------------------------------------------------------------------
__global__ __launch_bounds__(256) void logits_k(
    const float* __restrict__ X, const float* __restrict__ Wl,
    const float* __restrict__ bl, float* __restrict__ lgw)
{
    const int wid  = threadIdx.x >> 6;
    const int lane = threadIdx.x & 63;
    const int row  = blockIdx.x * 4 + wid;
    const float* xp = X + (size_t)row * H_;

    float acc[D_] = {0.f, 0.f, 0.f, 0.f};
    for (int h = lane * 4; h < H_; h += 256) {
        const f32x4 xv = *(const f32x4*)(xp + h);
#pragma unroll
        for (int d = 0; d < D_; ++d) {
            const f32x4 wv = *(const f32x4*)(Wl + d * H_ + h);
            acc[d] += xv[0] * wv[0] + xv[1] * wv[1] + xv[2] * wv[2] + xv[3] * wv[3];
        }
    }
#pragma unroll
    for (int off = 32; off; off >>= 1)
#pragma unroll
        for (int d = 0; d < D_; ++d) acc[d] += __shfl_xor(acc[d], off, 64);

    if (lane == 0) {
        float l[D_];
#pragma unroll
        for (int d = 0; d < D_; ++d) l[d] = acc[d] + bl[d];
        const float mx = fmaxf(fmaxf(l[0], l[1]), fmaxf(l[2], l[3]));
        float e[D_], s = 0.f;
#pragma unroll
        for (int d = 0; d < D_; ++d) { e[d] = __expf(l[d] - mx); s += e[d]; }
        const float inv = 1.0f / s;
        f32x4 o;
#pragma unroll
        for (int d = 0; d < D_; ++d) o[d] = e[d] * inv;
        *(f32x4*)(lgw + (size_t)row * 4) = o;
    }
}

// ---------------------------------------------------------------------------
__global__ void decstate_k(const float* __restrict__ state,
                           const float* __restrict__ tdm,
                           float* __restrict__ dec)
{
    const int i = blockIdx.x * blockDim.x + threadIdx.x;
    if (i >= B_ * D_ * H_) return;
    const int dh = i & (D_ * H_ - 1);
    dec[i] = state[i] * __expf(-__expf(tdm[dh]));
}

// ---------------------------------------------------------------------------
// new_state[b,d,h] = dec[b,d,h] + k_last*v_last, all-f32 exact path.
// ---------------------------------------------------------------------------
__global__ __launch_bounds__(256) void newstate_k(
    const float* __restrict__ X, const float* __restrict__ Wk,
    const float* __restrict__ Wv, const float* __restrict__ dec,
    float* __restrict__ out2)
{
    const int wid  = threadIdx.x >> 6;
    const int lane = threadIdx.x & 63;
    const int row  = blockIdx.x * 4 + wid;   // 0..B*H-1
    const int b    = row >> 10;
    const int h    = row & (H_ - 1);
    const float* xp = X + ((size_t)(b * T_ + (T_ - 1))) * H_;

    float ak = 0.f, av = 0.f;
    for (int j = lane * 4; j < H_; j += 256) {
        const f32x4 xv = *(const f32x4*)(xp + j);
        const f32x4 wk = *(const f32x4*)(Wk + (size_t)h * H_ + j);
        const f32x4 wv = *(const f32x4*)(Wv + (size_t)h * H_ + j);
        ak += xv[0]*wk[0] + xv[1]*wk[1] + xv[2]*wk[2] + xv[3]*wk[3];
        av += xv[0]*wv[0] + xv[1]*wv[1] + xv[2]*wv[2] + xv[3]*wv[3];
    }
#pragma unroll
    for (int off = 32; off; off >>= 1) {
        ak += __shfl_xor(ak, off, 64);
        av += __shfl_xor(av, off, 64);
    }
    if (lane == 0) {
        const float kv = ak * av;
#pragma unroll
        for (int d = 0; d < D_; ++d)
            out2[(size_t)(b * D_ + d) * H_ + h] = dec[(b * D_ + d) * H_ + h] + kv;
    }
}

// ---------------------------------------------------------------------------
extern "C" void kernel_launch(void* const* d_in, const int* in_sizes, int n_in,
                              void* d_out, int out_size, void* d_ws, size_t ws_size,
                              hipStream_t stream)
{
    const float* x   = (const float*)d_in[0];
    const float* st  = (const float*)d_in[1];
    const float* tdm = (const float*)d_in[2];
    const float* Wl  = (const float*)d_in[3];
    const float* bl  = (const float*)d_in[4];
    const float* Wv  = (const float*)d_in[5];
    const float* Wk  = (const float*)d_in[6];
    const float* Wr  = (const float*)d_in[7];
    const float* Wo  = (const float*)d_in[8];
    float* out = (float*)d_out;                    // f32 output

    char* ws = (char*)d_ws;
    unsigned short* buf  = (unsigned short*)(ws + WS_BUF);   // k -> kv -> o
    unsigned short* wk_b = (unsigned short*)(ws + WS_WK);    // [4][H][H]: k,v,r,o
    unsigned short* wv_b = wk_b + 1 * (H_ * H_);
    unsigned short* wr_b = wk_b + 2 * (H_ * H_);
    unsigned short* wo_b = wk_b + 3 * (H_ * H_);
    float* lgw = (float*)(ws + WS_LGW);
    float* dec = (float*)(ws + WS_DEC);

    // bf16 x scratch inside d_out's f32 output-0 region; final GEMM
    // fully overwrites it afterwards.
    unsigned short* xb = (unsigned short*)out;

    // small f32 kernels (depend only on raw inputs)
    logits_k<<<M_ / 4, 256, 0, stream>>>(x, Wl, bl, lgw);
    decstate_k<<<(B_ * D_ * H_ + 255) / 256, 256, 0, stream>>>(st, tdm, dec);
    newstate_k<<<(B_ * H_) / 4, 256, 0, stream>>>(x, Wk, Wv, dec, out + OUT_MAIN);

    // conversions
    cvt_k<<<2048, 256, 0, stream>>>(x, xb, OUT_MAIN / 4);
    cvtw_k<<<dim3(1024, 4), 256, 0, stream>>>(Wk, Wv, Wr, Wo, wk_b);

    const dim3 g(M_ / 256, H_ / 256), blk(512);

    // buf = k
    hipLaunchKernelGGL((gemm8p<0>), g, blk, 0, stream, xb, wk_b, buf,
                       (float*)nullptr, (const float*)nullptr, (const float*)nullptr);
    // buf = kv
    hipLaunchKernelGGL((gemm8p<1>), g, blk, 0, stream, xb, wv_b, buf,
                       (float*)nullptr, (const float*)nullptr, (const float*)nullptr);
    // buf = o = sigmoid(x@Wr^T) * (lw.dec + wsum*kv)
    hipLaunchKernelGGL((gemm8p<2>), g, blk, 0, stream, xb, wr_b, buf,
                       (float*)nullptr, (const float*)lgw, (const float*)dec);
    // out = f32(o @ Wo^T)
    hipLaunchKernelGGL((gemm8p<3>), g, blk, 0, stream, buf, wo_b, (unsigned short*)nullptr,
                       out, (const float*)nullptr, (const float*)nullptr);
}